// Round 3
// baseline (670.988 us; speedup 1.0000x reference)
//
#include <hip/hip_runtime.h>
#include <cstddef>

#define N_NODES  50000
#define N_EDGES  800000
#define HDIM     128
#define SSUB     5000
#define GGRAPH   64

typedef unsigned int uint;
typedef unsigned short ushort;
typedef __attribute__((ext_vector_type(8))) short bf16x8;
typedef __attribute__((ext_vector_type(4))) float f32x4;

// bf16 helpers (packed pair in a uint: low ushort = even feature, high = odd)
__device__ __forceinline__ float bflo(uint v) { return __uint_as_float(v << 16); }
__device__ __forceinline__ float bfhi(uint v) { return __uint_as_float(v & 0xffff0000u); }
__device__ __forceinline__ uint packbf(float lo, float hi) {
    uint a = __float_as_uint(lo), b = __float_as_uint(hi);
    a = (a + 0x7fff + ((a >> 16) & 1)) >> 16;          // RNE
    b = (b + 0x7fff + ((b >> 16) & 1)) & 0xffff0000u;  // RNE, keep high half
    return a | b;
}
__device__ __forceinline__ ushort bf16of(float f) {
    uint a = __float_as_uint(f);
    a = (a + 0x7fff + ((a >> 16) & 1)) >> 16;
    return (ushort)a;
}

// ---------------------------------------------------------------------------
// CSR build: histogram of dst, exclusive scan -> rowptr, bucketed 2-pass fill.
// ---------------------------------------------------------------------------

__global__ __launch_bounds__(256) void k_hist(const int* __restrict__ dst,
                                              int* __restrict__ cnt) {
    int e = blockIdx.x * 256 + threadIdx.x;   // grid = E/256 exact
    atomicAdd(&cnt[dst[e]], 1);
}

__global__ __launch_bounds__(256) void k_scan_reduce(const int* __restrict__ cnt,
                                                     int* __restrict__ bsum) {
    __shared__ int sd[256];
    int idx = blockIdx.x * 256 + threadIdx.x;
    int t = threadIdx.x;
    sd[t] = (idx < N_NODES) ? cnt[idx] : 0;
    __syncthreads();
    for (int off = 128; off > 0; off >>= 1) {
        if (t < off) sd[t] += sd[t + off];
        __syncthreads();
    }
    if (t == 0) bsum[blockIdx.x] = sd[0];
}

__global__ __launch_bounds__(256) void k_scan_top(const int* __restrict__ bsum,
                                                  int* __restrict__ boff, int nb) {
    __shared__ int sd[256];
    int t = threadIdx.x;
    sd[t] = (t < nb) ? bsum[t] : 0;
    __syncthreads();
    for (int off = 1; off < 256; off <<= 1) {
        int v = (t >= off) ? sd[t - off] : 0;
        __syncthreads();
        sd[t] += v;
        __syncthreads();
    }
    boff[t] = (t == 0) ? 0 : sd[t - 1];   // exclusive block offsets
}

__global__ __launch_bounds__(256) void k_scan_final(const int* __restrict__ cnt,
                                                    const int* __restrict__ boff,
                                                    int* __restrict__ rowptr) {
    __shared__ int sd[256];
    int idx = blockIdx.x * 256 + threadIdx.x;
    int t = threadIdx.x;
    int v = (idx < N_NODES) ? cnt[idx] : 0;
    sd[t] = v;
    __syncthreads();
    for (int off = 1; off < 256; off <<= 1) {
        int u = (t >= off) ? sd[t - off] : 0;
        __syncthreads();
        sd[t] += u;
        __syncthreads();
    }
    if (idx < N_NODES) rowptr[idx] = sd[t] - v + boff[blockIdx.x];  // exclusive
    if (idx == 0) rowptr[N_NODES] = N_EDGES;
}

// Pass A: append (src,dst) into the bucket's contiguous region of ebuf.
// bucket b = dst>>6 owns pair-range [rowptr[b<<6], rowptr[(b+1)<<6]).
__global__ __launch_bounds__(256) void k_bucket(const int* __restrict__ src,
                                                const int* __restrict__ dst,
                                                const int* __restrict__ rowptr,
                                                int* __restrict__ bcur,
                                                int2* __restrict__ ebuf) {
    int e = blockIdx.x * 256 + threadIdx.x;   // grid = E/256 exact
    int d = dst[e], s = src[e];
    int b = d >> 6;
    int base = rowptr[b << 6];
    int p = atomicAdd(&bcur[b], 1);
    ebuf[base + p] = make_int2(s, d);
}

// Pass B: within-bucket scatter; each bucket's csrc window (~4 KB) is
// L2-resident so lines are filled before writeback.
__global__ __launch_bounds__(256) void k_place(const int2* __restrict__ ebuf,
                                               const int* __restrict__ rowptr,
                                               int* __restrict__ cur,
                                               int* __restrict__ csrc) {
    int e = blockIdx.x * 256 + threadIdx.x;   // grid = E/256 exact
    int2 p = ebuf[e];
    int pos = rowptr[p.y] + atomicAdd(&cur[p.y], 1);
    csrc[pos] = p.x;
}

// ---------------------------------------------------------------------------
// Weight convert: 7 mats (W1b, cWa[0..2], cWb[0..2]) -> bf16, TRANSPOSED
// (wt[m][n][k] = W[k][n]) so MFMA B-frag loads are 16B-contiguous.
// ---------------------------------------------------------------------------

__global__ __launch_bounds__(256) void k_wconv(const float* __restrict__ W1b,
                                               const float* __restrict__ cWa,
                                               const float* __restrict__ cWb,
                                               ushort* __restrict__ wt) {
    int gid = blockIdx.x * 256 + threadIdx.x;   // grid = 7*16384/256 exact
    int m = gid >> 14, r = gid & 16383;
    int n = r >> 7, k = r & 127;
    const float* Wsrc = (m == 0) ? W1b
                      : (m <= 3) ? cWa + (size_t)(m - 1) * 16384
                                 : cWb + (size_t)(m - 4) * 16384;
    wt[gid] = bf16of(Wsrc[k * 128 + n]);
}

// ---------------------------------------------------------------------------
// Conv 1 front, fused: aggregate x (F_IN=2) + W1a (2x128) + bias + relu -> bf16
// ---------------------------------------------------------------------------

__global__ __launch_bounds__(256) void k_conv1(const float2* __restrict__ x,
                                               const int* __restrict__ rowptr,
                                               const int* __restrict__ csrc,
                                               const float* __restrict__ W1a,
                                               const float* __restrict__ b1a,
                                               uint* __restrict__ h1) {
    __shared__ float w[256];
    __shared__ float bb[128];
    w[threadIdx.x] = W1a[threadIdx.x];
    if (threadIdx.x < 128) bb[threadIdx.x] = b1a[threadIdx.x];
    __syncthreads();
    int n = blockIdx.x * 256 + threadIdx.x;
    if (n >= N_NODES) return;
    int s = rowptr[n], e = rowptr[n + 1];
    float2 a = x[n];
    for (int k = s; k < e; ++k) { float2 v = x[csrc[k]]; a.x += v.x; a.y += v.y; }
#pragma unroll 8
    for (int c = 0; c < 64; ++c) {
        int j0 = 2 * c, j1 = 2 * c + 1;
        float v0 = fmaf(a.x, w[j0], fmaf(a.y, w[128 + j0], bb[j0]));
        float v1 = fmaf(a.x, w[j1], fmaf(a.y, w[128 + j1], bb[j1]));
        h1[(size_t)n * 64 + c] = packbf(fmaxf(v0, 0.f), fmaxf(v1, 0.f));
    }
}

// ---------------------------------------------------------------------------
// GIN aggregation, H=128, bf16 in/out: one wave per node, lane holds one uint
// (2 bf16 features). out[n] = h[n] + sum_{src in-edges} h[src]  (fp32 accum)
// ---------------------------------------------------------------------------

__global__ __launch_bounds__(256) void k_aggr128_bf16(const uint* __restrict__ hb,
                                                      const int* __restrict__ rowptr,
                                                      const int* __restrict__ csrc,
                                                      uint* __restrict__ out) {
    int node = blockIdx.x * 4 + (threadIdx.x >> 6);   // grid = N/4 exact
    int lane = threadIdx.x & 63;
    int s = rowptr[node], e = rowptr[node + 1];
    uint sv = hb[(size_t)node * 64 + lane];
    float ax0 = bflo(sv), ay0 = bfhi(sv);
    float ax1 = 0.f, ay1 = 0.f, ax2 = 0.f, ay2 = 0.f, ax3 = 0.f, ay3 = 0.f;
    for (int base = s; base < e; base += 64) {
        int cnt = e - base; if (cnt > 64) cnt = 64;
        int idx = csrc[base + ((lane < cnt) ? lane : 0)];   // coalesced list load
        int j = 0;
        for (; j + 3 < cnt; j += 4) {
            int s0 = __shfl(idx, j),     s1 = __shfl(idx, j + 1);
            int s2 = __shfl(idx, j + 2), s3 = __shfl(idx, j + 3);
            uint v0 = hb[(size_t)s0 * 64 + lane];
            uint v1 = hb[(size_t)s1 * 64 + lane];
            uint v2 = hb[(size_t)s2 * 64 + lane];
            uint v3 = hb[(size_t)s3 * 64 + lane];
            ax0 += bflo(v0); ay0 += bfhi(v0);
            ax1 += bflo(v1); ay1 += bfhi(v1);
            ax2 += bflo(v2); ay2 += bfhi(v2);
            ax3 += bflo(v3); ay3 += bfhi(v3);
        }
        for (; j < cnt; ++j) {
            int sj = __shfl(idx, j);
            uint v = hb[(size_t)sj * 64 + lane];
            ax0 += bflo(v); ay0 += bfhi(v);
        }
    }
    out[(size_t)node * 64 + lane] =
        packbf((ax0 + ax1) + (ax2 + ax3), (ay0 + ay1) + (ay2 + ay3));
}

// ---------------------------------------------------------------------------
// bf16 MFMA GEMM: C[n][j] = relu(sum_k A[n][k]*W[k][j] + bias[j]), K=128,
// 128 cols, bf16 in/out, fp32 accum. 128-row tile/block, 4 waves x 32 rows.
// No LDS: A-frags 16B-contiguous from row-major A; B-frags from transposed Wt
// (L1-resident 32 KB). In-place safe (wave reads only its own 32 rows, all
// loads precede stores).
// A-frag layout: A[m=lane&15][k=quad*8+j]; C/D: col=lane&15, row=quad*4+reg.
// ---------------------------------------------------------------------------

__global__ __launch_bounds__(256) void k_gemm_mfma(const ushort* A,
                                                   const ushort* __restrict__ Wt,
                                                   const float* __restrict__ bias,
                                                   ushort* C, int nrows) {
    const int wave = threadIdx.x >> 6;
    const int lane = threadIdx.x & 63;
    const int quad = lane >> 4;
    const int l16  = lane & 15;
    const int rowBase = blockIdx.x * 128 + wave * 32;   // wave owns rows rowBase..+31

    f32x4 acc[2][8];
#pragma unroll
    for (int m = 0; m < 2; ++m)
#pragma unroll
        for (int c = 0; c < 8; ++c) acc[m][c] = (f32x4){0.f, 0.f, 0.f, 0.f};

    const int r0 = rowBase + l16;
    const int r1 = rowBase + 16 + l16;
#pragma unroll
    for (int kk = 0; kk < 4; ++kk) {
        const int k0 = kk * 32 + quad * 8;
        bf16x8 a0 = (bf16x8){0,0,0,0,0,0,0,0};
        bf16x8 a1 = (bf16x8){0,0,0,0,0,0,0,0};
        if (r0 < nrows) a0 = *(const bf16x8*)(A + (size_t)r0 * 128 + k0);
        if (r1 < nrows) a1 = *(const bf16x8*)(A + (size_t)r1 * 128 + k0);
#pragma unroll
        for (int c = 0; c < 8; ++c) {
            bf16x8 b = *(const bf16x8*)(Wt + (size_t)(c * 16 + l16) * 128 + k0);
            acc[0][c] = __builtin_amdgcn_mfma_f32_16x16x32_bf16(a0, b, acc[0][c], 0, 0, 0);
            acc[1][c] = __builtin_amdgcn_mfma_f32_16x16x32_bf16(a1, b, acc[1][c], 0, 0, 0);
        }
    }
#pragma unroll
    for (int m = 0; m < 2; ++m) {
        const int rb = rowBase + m * 16 + quad * 4;
#pragma unroll
        for (int c = 0; c < 8; ++c) {
            const int col = c * 16 + l16;
            const float bv = bias[col];
#pragma unroll
            for (int r = 0; r < 4; ++r) {
                int row = rb + r;
                if (row < nrows)
                    C[(size_t)row * 128 + col] = bf16of(fmaxf(acc[m][c][r] + bv, 0.f));
            }
        }
    }
}

// ---------------------------------------------------------------------------
// Pooling: node -> subgraph -> graph (atomic fadd, accumulators L2-resident).
// ---------------------------------------------------------------------------

__global__ __launch_bounds__(256) void k_pool1(const uint* __restrict__ hb,
                                               const int* __restrict__ n2s,
                                               float* __restrict__ poolS) {
    int gid = blockIdx.x * 256 + threadIdx.x;   // grid = N*64/256 exact
    int n = gid >> 6, c = gid & 63;
    uint v = hb[gid];
    int sg = n2s[n];
    atomicAdd(&poolS[(size_t)sg * 128 + 2 * c],     bflo(v));
    atomicAdd(&poolS[(size_t)sg * 128 + 2 * c + 1], bfhi(v));
}

__global__ __launch_bounds__(256) void k_pool2(const float* __restrict__ poolS,
                                               const int* __restrict__ s2g,
                                               float* __restrict__ poolG) {
    int gid = blockIdx.x * 256 + threadIdx.x;   // grid = S*128/256 exact
    int s = gid >> 7, j = gid & 127;
    atomicAdd(&poolG[(size_t)s2g[s] * 128 + j], poolS[gid]);
}

// ---------------------------------------------------------------------------
// Final MLP + log_softmax: one block per graph (G=64), 128 threads. fp32.
// ---------------------------------------------------------------------------

__global__ __launch_bounds__(128) void k_final(const float* __restrict__ poolG,
                                               const float* __restrict__ W1,
                                               const float* __restrict__ b1,
                                               const float* __restrict__ W2,
                                               const float* __restrict__ b2,
                                               float* __restrict__ out) {
    __shared__ float row[128];
    __shared__ float t1[128];
    __shared__ float red[128];
    int g = blockIdx.x, j = threadIdx.x;
    row[j] = poolG[g * 128 + j];
    __syncthreads();
    float s = b1[j];
    for (int k = 0; k < 128; ++k) s = fmaf(row[k], W1[k * 128 + j], s);
    t1[j] = fmaxf(s, 0.f);
    __syncthreads();
    float s2 = b2[j];
    for (int k = 0; k < 128; ++k) s2 = fmaf(t1[k], W2[k * 128 + j], s2);
    red[j] = s2;
    __syncthreads();
    for (int off = 64; off > 0; off >>= 1) {
        if (j < off) red[j] = fmaxf(red[j], red[j + off]);
        __syncthreads();
    }
    float m = red[0];
    __syncthreads();
    red[j] = expf(s2 - m);
    __syncthreads();
    for (int off = 64; off > 0; off >>= 1) {
        if (j < off) red[j] += red[j + off];
        __syncthreads();
    }
    float lse = m + logf(red[0]);
    out[g * 128 + j] = s2 - lse;
}

// ---------------------------------------------------------------------------

extern "C" void kernel_launch(void* const* d_in, const int* in_sizes, int n_in,
                              void* d_out, int out_size, void* d_ws, size_t ws_size,
                              hipStream_t stream) {
    (void)in_sizes; (void)n_in; (void)out_size; (void)ws_size;
    const float* x    = (const float*)d_in[0];
    const int*   ei   = (const int*)d_in[1];
    const int*   n2s  = (const int*)d_in[2];
    const int*   s2g  = (const int*)d_in[3];
    const float* W1a  = (const float*)d_in[4];
    const float* b1a  = (const float*)d_in[5];
    const float* W1b  = (const float*)d_in[6];
    const float* b1b  = (const float*)d_in[7];
    const float* cWa  = (const float*)d_in[8];
    const float* cba  = (const float*)d_in[9];
    const float* cWb  = (const float*)d_in[10];
    const float* cbb  = (const float*)d_in[11];
    const float* l1W  = (const float*)d_in[12];
    const float* l1b  = (const float*)d_in[13];
    const float* l2W  = (const float*)d_in[14];
    const float* l2b  = (const float*)d_in[15];
    float* out = (float*)d_out;

    // workspace layout (~38.5 MB)
    uint*  hb     = (uint*)d_ws;                        // N*64 (bf16 h, packed)
    uint*  habuf  = hb + (size_t)N_NODES * 64;          // N*64 (aggr / gemmA buf)
    int*   rowptr = (int*)(habuf + (size_t)N_NODES * 64); // N+2
    int*   cnt    = rowptr + (N_NODES + 2);             // N (hist, then place-cursor)
    int*   bsum   = cnt + N_NODES;                      // 256
    int*   boff   = bsum + 256;                         // 256
    int*   bcur   = boff + 256;                         // 1024 (bucket cursors)
    int*   csrc   = bcur + 1024;                        // E
    int2*  ebuf   = (int2*)(csrc + N_EDGES);            // E pairs
    float* poolS  = (float*)(ebuf + N_EDGES);           // S*128
    float* poolG  = poolS + (size_t)SSUB * HDIM;        // G*128
    ushort* wt    = (ushort*)(poolG + (size_t)GGRAPH * HDIM); // 7*16384 bf16

    const int* srcA = ei;
    const int* dstA = ei + N_EDGES;
    const int nScanBlocks = (N_NODES + 255) / 256;      // 196
    const int nGemmBlocks = (N_NODES + 127) / 128;      // 391

    // --- CSR build (bucketed fill) ---
    hipMemsetAsync(cnt, 0, N_NODES * sizeof(int), stream);
    hipMemsetAsync(bcur, 0, 1024 * sizeof(int), stream);
    hipMemsetAsync(poolS, 0, (size_t)(SSUB + GGRAPH) * HDIM * sizeof(float), stream);
    k_hist<<<N_EDGES / 256, 256, 0, stream>>>(dstA, cnt);
    k_scan_reduce<<<nScanBlocks, 256, 0, stream>>>(cnt, bsum);
    k_scan_top<<<1, 256, 0, stream>>>(bsum, boff, nScanBlocks);
    k_scan_final<<<nScanBlocks, 256, 0, stream>>>(cnt, boff, rowptr);
    hipMemsetAsync(cnt, 0, N_NODES * sizeof(int), stream);   // reuse as place cursor
    k_bucket<<<N_EDGES / 256, 256, 0, stream>>>(srcA, dstA, rowptr, bcur, ebuf);
    k_place<<<N_EDGES / 256, 256, 0, stream>>>(ebuf, rowptr, cnt, csrc);

    // --- weights -> bf16 transposed ---
    k_wconv<<<(7 * 16384) / 256, 256, 0, stream>>>(W1b, cWa, cWb, wt);

    // --- conv 1: fused aggr(x)+lin1a -> bf16, then MFMA gemm(W1b) -> hb ---
    k_conv1<<<nScanBlocks, 256, 0, stream>>>((const float2*)x, rowptr, csrc, W1a, b1a, habuf);
    k_gemm_mfma<<<nGemmBlocks, 256, 0, stream>>>((const ushort*)habuf, wt, b1b,
                                                 (ushort*)hb, N_NODES);

    // --- convs 2..4: aggr(hb)->habuf, gemmA in-place, gemmB -> hb ---
    for (int i = 0; i < 3; ++i) {
        k_aggr128_bf16<<<N_NODES / 4, 256, 0, stream>>>(hb, rowptr, csrc, habuf);
        k_gemm_mfma<<<nGemmBlocks, 256, 0, stream>>>((const ushort*)habuf,
                                                     wt + (size_t)(1 + i) * 16384,
                                                     cba + i * HDIM,
                                                     (ushort*)habuf, N_NODES);
        k_gemm_mfma<<<nGemmBlocks, 256, 0, stream>>>((const ushort*)habuf,
                                                     wt + (size_t)(4 + i) * 16384,
                                                     cbb + i * HDIM,
                                                     (ushort*)hb, N_NODES);
    }

    // --- pooling + head ---
    k_pool1<<<(N_NODES * 64) / 256, 256, 0, stream>>>(hb, n2s, poolS);
    k_pool2<<<(SSUB * HDIM) / 256, 256, 0, stream>>>(poolS, s2g, poolG);
    k_final<<<GGRAPH, 128, 0, stream>>>(poolG, l1W, l1b, l2W, l2b, out);
}

// Round 4
// 592.066 us; speedup vs baseline: 1.1333x; 1.1333x over previous
//
#include <hip/hip_runtime.h>
#include <cstddef>

#define N_NODES  50000
#define N_EDGES  800000
#define HDIM     128
#define SSUB     5000
#define GGRAPH   64
#define FILL_Q   416   // blocks per part in k_fill2 (grid = 8*FILL_Q)

typedef unsigned int uint;
typedef unsigned short ushort;
typedef __attribute__((ext_vector_type(8))) short bf16x8;
typedef __attribute__((ext_vector_type(4))) float f32x4;

// bf16 helpers (packed pair in a uint: low ushort = even feature, high = odd)
__device__ __forceinline__ float bflo(uint v) { return __uint_as_float(v << 16); }
__device__ __forceinline__ float bfhi(uint v) { return __uint_as_float(v & 0xffff0000u); }
__device__ __forceinline__ uint packbf(float lo, float hi) {
    uint a = __float_as_uint(lo), b = __float_as_uint(hi);
    a = (a + 0x7fff + ((a >> 16) & 1)) >> 16;          // RNE
    b = (b + 0x7fff + ((b >> 16) & 1)) & 0xffff0000u;  // RNE, keep high half
    return a | b;
}
__device__ __forceinline__ ushort bf16of(float f) {
    uint a = __float_as_uint(f);
    a = (a + 0x7fff + ((a >> 16) & 1)) >> 16;
    return (ushort)a;
}

// ---------------------------------------------------------------------------
// CSR build: hist (also records per-edge rank via atomic return), scan,
// then XCD-partitioned scatter with NO atomics.
// ---------------------------------------------------------------------------

__global__ __launch_bounds__(256) void k_hist2(const int* __restrict__ dst,
                                               int* __restrict__ cnt,
                                               int* __restrict__ rank) {
    int e = blockIdx.x * 256 + threadIdx.x;   // grid = E/256 exact
    rank[e] = atomicAdd(&cnt[dst[e]], 1);     // any permutation is a valid rank
}

__global__ __launch_bounds__(256) void k_scan_reduce(const int* __restrict__ cnt,
                                                     int* __restrict__ bsum) {
    __shared__ int sd[256];
    int idx = blockIdx.x * 256 + threadIdx.x;
    int t = threadIdx.x;
    sd[t] = (idx < N_NODES) ? cnt[idx] : 0;
    __syncthreads();
    for (int off = 128; off > 0; off >>= 1) {
        if (t < off) sd[t] += sd[t + off];
        __syncthreads();
    }
    if (t == 0) bsum[blockIdx.x] = sd[0];
}

__global__ __launch_bounds__(256) void k_scan_top(const int* __restrict__ bsum,
                                                  int* __restrict__ boff, int nb) {
    __shared__ int sd[256];
    int t = threadIdx.x;
    sd[t] = (t < nb) ? bsum[t] : 0;
    __syncthreads();
    for (int off = 1; off < 256; off <<= 1) {
        int v = (t >= off) ? sd[t - off] : 0;
        __syncthreads();
        sd[t] += v;
        __syncthreads();
    }
    boff[t] = (t == 0) ? 0 : sd[t - 1];   // exclusive block offsets
}

__global__ __launch_bounds__(256) void k_scan_final(const int* __restrict__ cnt,
                                                    const int* __restrict__ boff,
                                                    int* __restrict__ rowptr) {
    __shared__ int sd[256];
    int idx = blockIdx.x * 256 + threadIdx.x;
    int t = threadIdx.x;
    int v = (idx < N_NODES) ? cnt[idx] : 0;
    sd[t] = v;
    __syncthreads();
    for (int off = 1; off < 256; off <<= 1) {
        int u = (t >= off) ? sd[t - off] : 0;
        __syncthreads();
        sd[t] += u;
        __syncthreads();
    }
    if (idx < N_NODES) rowptr[idx] = sd[t] - v + boff[blockIdx.x];  // exclusive
    if (idx == 0) rowptr[N_NODES] = N_EDGES;
}

// XCD-partitioned scatter: part = blockIdx&7 handles dst in its 6250-node
// range; that part's csrc window (~400 KB) stays L2-resident on one XCD, so
// lines are written back once (kills the 17x scatter write amplification).
__global__ __launch_bounds__(256) void k_fill2(const int* __restrict__ src,
                                               const int* __restrict__ dst,
                                               const int* __restrict__ rank,
                                               const int* __restrict__ rowptr,
                                               int* __restrict__ csrc) {
    int part = blockIdx.x & 7;
    int q = blockIdx.x >> 3;
    int lo = part * 6250, hi = lo + 6250;
    for (int e = q * 256 + threadIdx.x; e < N_EDGES; e += FILL_Q * 256) {
        int d = dst[e];
        if (d >= lo && d < hi) csrc[rowptr[d] + rank[e]] = src[e];
    }
}

// ---------------------------------------------------------------------------
// Weight convert: 7 mats (W1b, cWa[0..2], cWb[0..2]) -> bf16, TRANSPOSED
// (wt[m][n][k] = W[k][n]) so MFMA B-frag loads are 16B-contiguous.
// ---------------------------------------------------------------------------

__global__ __launch_bounds__(256) void k_wconv(const float* __restrict__ W1b,
                                               const float* __restrict__ cWa,
                                               const float* __restrict__ cWb,
                                               ushort* __restrict__ wt) {
    int gid = blockIdx.x * 256 + threadIdx.x;   // grid = 7*16384/256 exact
    int m = gid >> 14, r = gid & 16383;
    int n = r >> 7, k = r & 127;
    const float* Wsrc = (m == 0) ? W1b
                      : (m <= 3) ? cWa + (size_t)(m - 1) * 16384
                                 : cWb + (size_t)(m - 4) * 16384;
    wt[gid] = bf16of(Wsrc[k * 128 + n]);
}

// ---------------------------------------------------------------------------
// Conv 1 front, fused: aggregate x (F_IN=2) + W1a (2x128) + bias + relu -> bf16
// ---------------------------------------------------------------------------

__global__ __launch_bounds__(256) void k_conv1(const float2* __restrict__ x,
                                               const int* __restrict__ rowptr,
                                               const int* __restrict__ csrc,
                                               const float* __restrict__ W1a,
                                               const float* __restrict__ b1a,
                                               uint* __restrict__ h1) {
    __shared__ float w[256];
    __shared__ float bb[128];
    w[threadIdx.x] = W1a[threadIdx.x];
    if (threadIdx.x < 128) bb[threadIdx.x] = b1a[threadIdx.x];
    __syncthreads();
    int n = blockIdx.x * 256 + threadIdx.x;
    if (n >= N_NODES) return;
    int s = rowptr[n], e = rowptr[n + 1];
    float2 a = x[n];
    for (int k = s; k < e; ++k) { float2 v = x[csrc[k]]; a.x += v.x; a.y += v.y; }
#pragma unroll 8
    for (int c = 0; c < 64; ++c) {
        int j0 = 2 * c, j1 = 2 * c + 1;
        float v0 = fmaf(a.x, w[j0], fmaf(a.y, w[128 + j0], bb[j0]));
        float v1 = fmaf(a.x, w[j1], fmaf(a.y, w[128 + j1], bb[j1]));
        h1[(size_t)n * 64 + c] = packbf(fmaxf(v0, 0.f), fmaxf(v1, 0.f));
    }
}

// ---------------------------------------------------------------------------
// Feature-sharded GIN aggregation: chunk = 32 features = 16 uints = 64 B
// (one cache line per edge-gather). chunk = blockIdx&3 -> XCD pair {c, c+4}
// keeps that 3.2 MB feature slice L2-resident. Wave = node x chunk; 64 lanes
// = 4 parallel edges x 16 feature-lanes; shfl-reduce across edge groups.
// out[n] = h[n] + sum_{src in-edges} h[src]   (fp32 accum, bf16 in/out)
// ---------------------------------------------------------------------------

__global__ __launch_bounds__(256) void k_aggr_shard(const uint* __restrict__ hb,
                                                    const int* __restrict__ rowptr,
                                                    const int* __restrict__ csrc,
                                                    uint* __restrict__ out) {
    int chunk = blockIdx.x & 3;                               // grid = (N/4)*4
    int node = (blockIdx.x >> 2) * 4 + (threadIdx.x >> 6);
    int lane = threadIdx.x & 63;
    int l16 = lane & 15, e4 = lane >> 4;
    const int cbase = chunk * 16 + l16;
    int s = rowptr[node], e = rowptr[node + 1];
    float ax = 0.f, ay = 0.f;
    if (e4 == 0) {                                            // self term
        uint sv = hb[(size_t)node * 64 + cbase];
        ax = bflo(sv); ay = bfhi(sv);
    }
    int k = s + e4;
    for (; k + 4 < e; k += 8) {                               // 2-way ILP
        int s0 = csrc[k], s1 = csrc[k + 4];
        uint v0 = hb[(size_t)s0 * 64 + cbase];
        uint v1 = hb[(size_t)s1 * 64 + cbase];
        ax += bflo(v0) + bflo(v1);
        ay += bfhi(v0) + bfhi(v1);
    }
    if (k < e) {
        uint v = hb[(size_t)csrc[k] * 64 + cbase];
        ax += bflo(v); ay += bfhi(v);
    }
    ax += __shfl_down(ax, 32); ay += __shfl_down(ay, 32);
    ax += __shfl_down(ax, 16); ay += __shfl_down(ay, 16);
    if (lane < 16)
        out[(size_t)node * 64 + chunk * 16 + lane] = packbf(ax, ay);
}

// ---------------------------------------------------------------------------
// bf16 MFMA GEMM: C[n][j] = relu(sum_k A[n][k]*W[k][j] + bias[j]), K=128,
// 128 cols, bf16 in/out, fp32 accum. 128-row tile/block, 4 waves x 32 rows.
// No LDS: A-frags 16B-contiguous from row-major A; B-frags from transposed Wt
// (L1-resident 32 KB). In-place safe (wave reads only its own 32 rows, all
// loads precede stores).
// ---------------------------------------------------------------------------

__global__ __launch_bounds__(256) void k_gemm_mfma(const ushort* A,
                                                   const ushort* __restrict__ Wt,
                                                   const float* __restrict__ bias,
                                                   ushort* C, int nrows) {
    const int wave = threadIdx.x >> 6;
    const int lane = threadIdx.x & 63;
    const int quad = lane >> 4;
    const int l16  = lane & 15;
    const int rowBase = blockIdx.x * 128 + wave * 32;   // wave owns rows rowBase..+31

    f32x4 acc[2][8];
#pragma unroll
    for (int m = 0; m < 2; ++m)
#pragma unroll
        for (int c = 0; c < 8; ++c) acc[m][c] = (f32x4){0.f, 0.f, 0.f, 0.f};

    const int r0 = rowBase + l16;
    const int r1 = rowBase + 16 + l16;
#pragma unroll
    for (int kk = 0; kk < 4; ++kk) {
        const int k0 = kk * 32 + quad * 8;
        bf16x8 a0 = (bf16x8){0,0,0,0,0,0,0,0};
        bf16x8 a1 = (bf16x8){0,0,0,0,0,0,0,0};
        if (r0 < nrows) a0 = *(const bf16x8*)(A + (size_t)r0 * 128 + k0);
        if (r1 < nrows) a1 = *(const bf16x8*)(A + (size_t)r1 * 128 + k0);
#pragma unroll
        for (int c = 0; c < 8; ++c) {
            bf16x8 b = *(const bf16x8*)(Wt + (size_t)(c * 16 + l16) * 128 + k0);
            acc[0][c] = __builtin_amdgcn_mfma_f32_16x16x32_bf16(a0, b, acc[0][c], 0, 0, 0);
            acc[1][c] = __builtin_amdgcn_mfma_f32_16x16x32_bf16(a1, b, acc[1][c], 0, 0, 0);
        }
    }
#pragma unroll
    for (int m = 0; m < 2; ++m) {
        const int rb = rowBase + m * 16 + quad * 4;
#pragma unroll
        for (int c = 0; c < 8; ++c) {
            const int col = c * 16 + l16;
            const float bv = bias[col];
#pragma unroll
            for (int r = 0; r < 4; ++r) {
                int row = rb + r;
                if (row < nrows)
                    C[(size_t)row * 128 + col] = bf16of(fmaxf(acc[m][c][r] + bv, 0.f));
            }
        }
    }
}

// ---------------------------------------------------------------------------
// Pooling: node -> subgraph -> graph (atomic fadd, accumulators L2-resident).
// ---------------------------------------------------------------------------

__global__ __launch_bounds__(256) void k_pool1(const uint* __restrict__ hb,
                                               const int* __restrict__ n2s,
                                               float* __restrict__ poolS) {
    int gid = blockIdx.x * 256 + threadIdx.x;   // grid = N*64/256 exact
    int n = gid >> 6, c = gid & 63;
    uint v = hb[gid];
    int sg = n2s[n];
    atomicAdd(&poolS[(size_t)sg * 128 + 2 * c],     bflo(v));
    atomicAdd(&poolS[(size_t)sg * 128 + 2 * c + 1], bfhi(v));
}

__global__ __launch_bounds__(256) void k_pool2(const float* __restrict__ poolS,
                                               const int* __restrict__ s2g,
                                               float* __restrict__ poolG) {
    int gid = blockIdx.x * 256 + threadIdx.x;   // grid = S*128/256 exact
    int s = gid >> 7, j = gid & 127;
    atomicAdd(&poolG[(size_t)s2g[s] * 128 + j], poolS[gid]);
}

// ---------------------------------------------------------------------------
// Final MLP + log_softmax: one block per graph (G=64), 128 threads. fp32.
// ---------------------------------------------------------------------------

__global__ __launch_bounds__(128) void k_final(const float* __restrict__ poolG,
                                               const float* __restrict__ W1,
                                               const float* __restrict__ b1,
                                               const float* __restrict__ W2,
                                               const float* __restrict__ b2,
                                               float* __restrict__ out) {
    __shared__ float row[128];
    __shared__ float t1[128];
    __shared__ float red[128];
    int g = blockIdx.x, j = threadIdx.x;
    row[j] = poolG[g * 128 + j];
    __syncthreads();
    float s = b1[j];
    for (int k = 0; k < 128; ++k) s = fmaf(row[k], W1[k * 128 + j], s);
    t1[j] = fmaxf(s, 0.f);
    __syncthreads();
    float s2 = b2[j];
    for (int k = 0; k < 128; ++k) s2 = fmaf(t1[k], W2[k * 128 + j], s2);
    red[j] = s2;
    __syncthreads();
    for (int off = 64; off > 0; off >>= 1) {
        if (j < off) red[j] = fmaxf(red[j], red[j + off]);
        __syncthreads();
    }
    float m = red[0];
    __syncthreads();
    red[j] = expf(s2 - m);
    __syncthreads();
    for (int off = 64; off > 0; off >>= 1) {
        if (j < off) red[j] += red[j + off];
        __syncthreads();
    }
    float lse = m + logf(red[0]);
    out[g * 128 + j] = s2 - lse;
}

// ---------------------------------------------------------------------------

extern "C" void kernel_launch(void* const* d_in, const int* in_sizes, int n_in,
                              void* d_out, int out_size, void* d_ws, size_t ws_size,
                              hipStream_t stream) {
    (void)in_sizes; (void)n_in; (void)out_size; (void)ws_size;
    const float* x    = (const float*)d_in[0];
    const int*   ei   = (const int*)d_in[1];
    const int*   n2s  = (const int*)d_in[2];
    const int*   s2g  = (const int*)d_in[3];
    const float* W1a  = (const float*)d_in[4];
    const float* b1a  = (const float*)d_in[5];
    const float* W1b  = (const float*)d_in[6];
    const float* b1b  = (const float*)d_in[7];
    const float* cWa  = (const float*)d_in[8];
    const float* cba  = (const float*)d_in[9];
    const float* cWb  = (const float*)d_in[10];
    const float* cbb  = (const float*)d_in[11];
    const float* l1W  = (const float*)d_in[12];
    const float* l1b  = (const float*)d_in[13];
    const float* l2W  = (const float*)d_in[14];
    const float* l2b  = (const float*)d_in[15];
    float* out = (float*)d_out;

    // workspace layout (~35 MB)
    uint*  hb     = (uint*)d_ws;                        // N*64 (bf16 h, packed)
    uint*  habuf  = hb + (size_t)N_NODES * 64;          // N*64 (aggr / gemmA buf)
    int*   rowptr = (int*)(habuf + (size_t)N_NODES * 64); // N+2
    int*   cnt    = rowptr + (N_NODES + 2);             // N
    int*   bsum   = cnt + N_NODES;                      // 256
    int*   boff   = bsum + 256;                         // 256
    int*   csrc   = boff + 256;                         // E
    int*   rank   = csrc + N_EDGES;                     // E
    float* poolS  = (float*)(rank + N_EDGES);           // S*128
    float* poolG  = poolS + (size_t)SSUB * HDIM;        // G*128
    ushort* wt    = (ushort*)(poolG + (size_t)GGRAPH * HDIM); // 7*16384 bf16

    const int* srcA = ei;
    const int* dstA = ei + N_EDGES;
    const int nScanBlocks = (N_NODES + 255) / 256;      // 196
    const int nGemmBlocks = (N_NODES + 127) / 128;      // 391

    // --- CSR build (rank-based, atomic-free partitioned fill) ---
    hipMemsetAsync(cnt, 0, N_NODES * sizeof(int), stream);
    hipMemsetAsync(poolS, 0, (size_t)(SSUB + GGRAPH) * HDIM * sizeof(float), stream);
    k_hist2<<<N_EDGES / 256, 256, 0, stream>>>(dstA, cnt, rank);
    k_scan_reduce<<<nScanBlocks, 256, 0, stream>>>(cnt, bsum);
    k_scan_top<<<1, 256, 0, stream>>>(bsum, boff, nScanBlocks);
    k_scan_final<<<nScanBlocks, 256, 0, stream>>>(cnt, boff, rowptr);
    k_fill2<<<8 * FILL_Q, 256, 0, stream>>>(srcA, dstA, rank, rowptr, csrc);

    // --- weights -> bf16 transposed ---
    k_wconv<<<(7 * 16384) / 256, 256, 0, stream>>>(W1b, cWa, cWb, wt);

    // --- conv 1: fused aggr(x)+lin1a -> bf16, then MFMA gemm(W1b) -> hb ---
    k_conv1<<<nScanBlocks, 256, 0, stream>>>((const float2*)x, rowptr, csrc, W1a, b1a, habuf);
    k_gemm_mfma<<<nGemmBlocks, 256, 0, stream>>>((const ushort*)habuf, wt, b1b,
                                                 (ushort*)hb, N_NODES);

    // --- convs 2..4: aggr(hb)->habuf, gemmA in-place, gemmB -> hb ---
    for (int i = 0; i < 3; ++i) {
        k_aggr_shard<<<(N_NODES / 4) * 4, 256, 0, stream>>>(hb, rowptr, csrc, habuf);
        k_gemm_mfma<<<nGemmBlocks, 256, 0, stream>>>((const ushort*)habuf,
                                                     wt + (size_t)(1 + i) * 16384,
                                                     cba + i * HDIM,
                                                     (ushort*)habuf, N_NODES);
        k_gemm_mfma<<<nGemmBlocks, 256, 0, stream>>>((const ushort*)habuf,
                                                     wt + (size_t)(4 + i) * 16384,
                                                     cbb + i * HDIM,
                                                     (ushort*)hb, N_NODES);
    }

    // --- pooling + head ---
    k_pool1<<<(N_NODES * 64) / 256, 256, 0, stream>>>(hb, n2s, poolS);
    k_pool2<<<(SSUB * HDIM) / 256, 256, 0, stream>>>(poolS, s2g, poolG);
    k_final<<<GGRAPH, 128, 0, stream>>>(poolG, l1W, l1b, l2W, l2b, out);
}

// Round 5
// 433.979 us; speedup vs baseline: 1.5461x; 1.3643x over previous
//
#include <hip/hip_runtime.h>
#include <cstddef>

#define N_NODES  50000
#define N_EDGES  800000
#define HDIM     128
#define SSUB     5000
#define GGRAPH   64
#define FILL_Q   416   // blocks per part in k_fill2 (grid = 8*FILL_Q)

typedef unsigned int uint;
typedef unsigned short ushort;
typedef __attribute__((ext_vector_type(8))) short bf16x8;
typedef __attribute__((ext_vector_type(4))) float f32x4;

// bf16 helpers (packed pair in a uint: low ushort = even feature, high = odd)
__device__ __forceinline__ float bflo(uint v) { return __uint_as_float(v << 16); }
__device__ __forceinline__ float bfhi(uint v) { return __uint_as_float(v & 0xffff0000u); }
__device__ __forceinline__ uint packbf(float lo, float hi) {
    uint a = __float_as_uint(lo), b = __float_as_uint(hi);
    a = (a + 0x7fff + ((a >> 16) & 1)) >> 16;          // RNE
    b = (b + 0x7fff + ((b >> 16) & 1)) & 0xffff0000u;  // RNE, keep high half
    return a | b;
}
__device__ __forceinline__ ushort bf16of(float f) {
    uint a = __float_as_uint(f);
    a = (a + 0x7fff + ((a >> 16) & 1)) >> 16;
    return (ushort)a;
}

// ---------------------------------------------------------------------------
// CSR build: hist (records per-edge rank via atomic return), scan,
// then XCD-partitioned scatter with NO atomics.
// ---------------------------------------------------------------------------

__global__ __launch_bounds__(256) void k_hist2(const int* __restrict__ dst,
                                               int* __restrict__ cnt,
                                               int* __restrict__ rank) {
    int e = blockIdx.x * 256 + threadIdx.x;   // grid = E/256 exact
    rank[e] = atomicAdd(&cnt[dst[e]], 1);     // any permutation is a valid rank
}

__global__ __launch_bounds__(256) void k_scan_reduce(const int* __restrict__ cnt,
                                                     int* __restrict__ bsum) {
    __shared__ int sd[256];
    int idx = blockIdx.x * 256 + threadIdx.x;
    int t = threadIdx.x;
    sd[t] = (idx < N_NODES) ? cnt[idx] : 0;
    __syncthreads();
    for (int off = 128; off > 0; off >>= 1) {
        if (t < off) sd[t] += sd[t + off];
        __syncthreads();
    }
    if (t == 0) bsum[blockIdx.x] = sd[0];
}

__global__ __launch_bounds__(256) void k_scan_top(const int* __restrict__ bsum,
                                                  int* __restrict__ boff, int nb) {
    __shared__ int sd[256];
    int t = threadIdx.x;
    sd[t] = (t < nb) ? bsum[t] : 0;
    __syncthreads();
    for (int off = 1; off < 256; off <<= 1) {
        int v = (t >= off) ? sd[t - off] : 0;
        __syncthreads();
        sd[t] += v;
        __syncthreads();
    }
    boff[t] = (t == 0) ? 0 : sd[t - 1];   // exclusive block offsets
}

__global__ __launch_bounds__(256) void k_scan_final(const int* __restrict__ cnt,
                                                    const int* __restrict__ boff,
                                                    int* __restrict__ rowptr) {
    __shared__ int sd[256];
    int idx = blockIdx.x * 256 + threadIdx.x;
    int t = threadIdx.x;
    int v = (idx < N_NODES) ? cnt[idx] : 0;
    sd[t] = v;
    __syncthreads();
    for (int off = 1; off < 256; off <<= 1) {
        int u = (t >= off) ? sd[t - off] : 0;
        __syncthreads();
        sd[t] += u;
        __syncthreads();
    }
    if (idx < N_NODES) rowptr[idx] = sd[t] - v + boff[blockIdx.x];  // exclusive
    if (idx == 0) rowptr[N_NODES] = N_EDGES;
}

// XCD-partitioned scatter: part = blockIdx&7 handles dst in its 6250-node
// range; that part's csrc window (~400 KB) stays L2-resident on one XCD, so
// lines are written back once (kills the 17x scatter write amplification).
__global__ __launch_bounds__(256) void k_fill2(const int* __restrict__ src,
                                               const int* __restrict__ dst,
                                               const int* __restrict__ rank,
                                               const int* __restrict__ rowptr,
                                               int* __restrict__ csrc) {
    int part = blockIdx.x & 7;
    int q = blockIdx.x >> 3;
    int lo = part * 6250, hi = lo + 6250;
    for (int e = q * 256 + threadIdx.x; e < N_EDGES; e += FILL_Q * 256) {
        int d = dst[e];
        if (d >= lo && d < hi) csrc[rowptr[d] + rank[e]] = src[e];
    }
}

// ---------------------------------------------------------------------------
// Weight convert: 7 mats (W1b, cWa[0..2], cWb[0..2]) -> bf16, TRANSPOSED
// (wt[m][n][k] = W[k][n]) so MFMA B-frag loads are 16B-contiguous.
// ---------------------------------------------------------------------------

__global__ __launch_bounds__(256) void k_wconv(const float* __restrict__ W1b,
                                               const float* __restrict__ cWa,
                                               const float* __restrict__ cWb,
                                               ushort* __restrict__ wt) {
    int gid = blockIdx.x * 256 + threadIdx.x;   // grid = 7*16384/256 exact
    int m = gid >> 14, r = gid & 16383;
    int n = r >> 7, k = r & 127;
    const float* Wsrc = (m == 0) ? W1b
                      : (m <= 3) ? cWa + (size_t)(m - 1) * 16384
                                 : cWb + (size_t)(m - 4) * 16384;
    wt[gid] = bf16of(Wsrc[k * 128 + n]);
}

// ---------------------------------------------------------------------------
// Conv 1 front, fused: aggregate x (F_IN=2) + W1a (2x128) + bias + relu -> bf16
// ---------------------------------------------------------------------------

__global__ __launch_bounds__(256) void k_conv1(const float2* __restrict__ x,
                                               const int* __restrict__ rowptr,
                                               const int* __restrict__ csrc,
                                               const float* __restrict__ W1a,
                                               const float* __restrict__ b1a,
                                               uint* __restrict__ h1) {
    __shared__ float w[256];
    __shared__ float bb[128];
    w[threadIdx.x] = W1a[threadIdx.x];
    if (threadIdx.x < 128) bb[threadIdx.x] = b1a[threadIdx.x];
    __syncthreads();
    int n = blockIdx.x * 256 + threadIdx.x;
    if (n >= N_NODES) return;
    int s = rowptr[n], e = rowptr[n + 1];
    float2 a = x[n];
    for (int k = s; k < e; ++k) { float2 v = x[csrc[k]]; a.x += v.x; a.y += v.y; }
#pragma unroll 8
    for (int c = 0; c < 64; ++c) {
        int j0 = 2 * c, j1 = 2 * c + 1;
        float v0 = fmaf(a.x, w[j0], fmaf(a.y, w[128 + j0], bb[j0]));
        float v1 = fmaf(a.x, w[j1], fmaf(a.y, w[128 + j1], bb[j1]));
        h1[(size_t)n * 64 + c] = packbf(fmaxf(v0, 0.f), fmaxf(v1, 0.f));
    }
}

// ---------------------------------------------------------------------------
// GIN aggregation, H=128, bf16 in/out: one wave per node, lane holds one uint
// (2 bf16 features), full 256 B row per gather (max line utilization), shfl
// broadcast of the coalesced csrc list, 8 outstanding gathers for MLP.
// out[n] = h[n] + sum_{src in-edges} h[src]  (fp32 accum)
// ---------------------------------------------------------------------------

__global__ __launch_bounds__(256) void k_aggr128_bf16(const uint* __restrict__ hb,
                                                      const int* __restrict__ rowptr,
                                                      const int* __restrict__ csrc,
                                                      uint* __restrict__ out) {
    int node = blockIdx.x * 4 + (threadIdx.x >> 6);   // grid = N/4 exact
    int lane = threadIdx.x & 63;
    int s = rowptr[node], e = rowptr[node + 1];
    uint sv = hb[(size_t)node * 64 + lane];
    float ax0 = bflo(sv), ay0 = bfhi(sv);
    float ax1 = 0.f, ay1 = 0.f, ax2 = 0.f, ay2 = 0.f, ax3 = 0.f, ay3 = 0.f;
    for (int base = s; base < e; base += 64) {
        int cnt = e - base; if (cnt > 64) cnt = 64;
        int idx = csrc[base + ((lane < cnt) ? lane : 0)];   // coalesced list load
        int j = 0;
        for (; j + 7 < cnt; j += 8) {                       // 8 outstanding gathers
            int s0 = __shfl(idx, j),     s1 = __shfl(idx, j + 1);
            int s2 = __shfl(idx, j + 2), s3 = __shfl(idx, j + 3);
            int s4 = __shfl(idx, j + 4), s5 = __shfl(idx, j + 5);
            int s6 = __shfl(idx, j + 6), s7 = __shfl(idx, j + 7);
            uint v0 = hb[(size_t)s0 * 64 + lane];
            uint v1 = hb[(size_t)s1 * 64 + lane];
            uint v2 = hb[(size_t)s2 * 64 + lane];
            uint v3 = hb[(size_t)s3 * 64 + lane];
            uint v4 = hb[(size_t)s4 * 64 + lane];
            uint v5 = hb[(size_t)s5 * 64 + lane];
            uint v6 = hb[(size_t)s6 * 64 + lane];
            uint v7 = hb[(size_t)s7 * 64 + lane];
            ax0 += bflo(v0); ay0 += bfhi(v0);
            ax1 += bflo(v1); ay1 += bfhi(v1);
            ax2 += bflo(v2); ay2 += bfhi(v2);
            ax3 += bflo(v3); ay3 += bfhi(v3);
            ax0 += bflo(v4); ay0 += bfhi(v4);
            ax1 += bflo(v5); ay1 += bfhi(v5);
            ax2 += bflo(v6); ay2 += bfhi(v6);
            ax3 += bflo(v7); ay3 += bfhi(v7);
        }
        for (; j < cnt; ++j) {
            int sj = __shfl(idx, j);
            uint v = hb[(size_t)sj * 64 + lane];
            ax0 += bflo(v); ay0 += bfhi(v);
        }
    }
    out[(size_t)node * 64 + lane] =
        packbf((ax0 + ax1) + (ax2 + ax3), (ay0 + ay1) + (ay2 + ay3));
}

// ---------------------------------------------------------------------------
// bf16 MFMA GEMM: C[n][j] = relu(sum_k A[n][k]*W[k][j] + bias[j]), K=128,
// 128 cols, bf16 in, fp32 accum. 128-row tile/block, 4 waves x 32 rows.
// No LDS: A-frags 16B-contiguous from row-major A; B-frags from transposed Wt
// (L1-resident 32 KB). In-place safe (wave reads only its own 32 rows, all
// loads precede stores).  POOL=1: instead of writing bf16 C rows, atomicAdd
// the fp32 relu outputs into poolS[n2s[row]] (fuses node->subgraph pooling).
// ---------------------------------------------------------------------------

template <int POOL>
__global__ __launch_bounds__(256) void k_gemm_mfma(const ushort* A,
                                                   const ushort* __restrict__ Wt,
                                                   const float* __restrict__ bias,
                                                   ushort* C,
                                                   const int* __restrict__ n2s,
                                                   float* __restrict__ poolS,
                                                   int nrows) {
    const int wave = threadIdx.x >> 6;
    const int lane = threadIdx.x & 63;
    const int quad = lane >> 4;
    const int l16  = lane & 15;
    const int rowBase = blockIdx.x * 128 + wave * 32;   // wave owns rows rowBase..+31

    f32x4 acc[2][8];
#pragma unroll
    for (int m = 0; m < 2; ++m)
#pragma unroll
        for (int c = 0; c < 8; ++c) acc[m][c] = (f32x4){0.f, 0.f, 0.f, 0.f};

    const int r0 = rowBase + l16;
    const int r1 = rowBase + 16 + l16;
#pragma unroll
    for (int kk = 0; kk < 4; ++kk) {
        const int k0 = kk * 32 + quad * 8;
        bf16x8 a0 = (bf16x8){0,0,0,0,0,0,0,0};
        bf16x8 a1 = (bf16x8){0,0,0,0,0,0,0,0};
        if (r0 < nrows) a0 = *(const bf16x8*)(A + (size_t)r0 * 128 + k0);
        if (r1 < nrows) a1 = *(const bf16x8*)(A + (size_t)r1 * 128 + k0);
#pragma unroll
        for (int c = 0; c < 8; ++c) {
            bf16x8 b = *(const bf16x8*)(Wt + (size_t)(c * 16 + l16) * 128 + k0);
            acc[0][c] = __builtin_amdgcn_mfma_f32_16x16x32_bf16(a0, b, acc[0][c], 0, 0, 0);
            acc[1][c] = __builtin_amdgcn_mfma_f32_16x16x32_bf16(a1, b, acc[1][c], 0, 0, 0);
        }
    }
#pragma unroll
    for (int m = 0; m < 2; ++m) {
#pragma unroll
        for (int r = 0; r < 4; ++r) {
            const int row = rowBase + m * 16 + quad * 4 + r;
            if (row >= nrows) continue;
            const int sg = POOL ? n2s[row] : 0;
#pragma unroll
            for (int c = 0; c < 8; ++c) {
                const int col = c * 16 + l16;
                float v = fmaxf(acc[m][c][r] + bias[col], 0.f);
                if (POOL) atomicAdd(&poolS[(size_t)sg * 128 + col], v);
                else      C[(size_t)row * 128 + col] = bf16of(v);
            }
        }
    }
}

// ---------------------------------------------------------------------------
// Pooling level 2: subgraph -> graph (atomic fadd, accumulators L2-resident).
// ---------------------------------------------------------------------------

__global__ __launch_bounds__(256) void k_pool2(const float* __restrict__ poolS,
                                               const int* __restrict__ s2g,
                                               float* __restrict__ poolG) {
    int gid = blockIdx.x * 256 + threadIdx.x;   // grid = S*128/256 exact
    int s = gid >> 7, j = gid & 127;
    atomicAdd(&poolG[(size_t)s2g[s] * 128 + j], poolS[gid]);
}

// ---------------------------------------------------------------------------
// Final MLP + log_softmax: one block per graph (G=64), 128 threads. fp32.
// ---------------------------------------------------------------------------

__global__ __launch_bounds__(128) void k_final(const float* __restrict__ poolG,
                                               const float* __restrict__ W1,
                                               const float* __restrict__ b1,
                                               const float* __restrict__ W2,
                                               const float* __restrict__ b2,
                                               float* __restrict__ out) {
    __shared__ float row[128];
    __shared__ float t1[128];
    __shared__ float red[128];
    int g = blockIdx.x, j = threadIdx.x;
    row[j] = poolG[g * 128 + j];
    __syncthreads();
    float s = b1[j];
    for (int k = 0; k < 128; ++k) s = fmaf(row[k], W1[k * 128 + j], s);
    t1[j] = fmaxf(s, 0.f);
    __syncthreads();
    float s2 = b2[j];
    for (int k = 0; k < 128; ++k) s2 = fmaf(t1[k], W2[k * 128 + j], s2);
    red[j] = s2;
    __syncthreads();
    for (int off = 64; off > 0; off >>= 1) {
        if (j < off) red[j] = fmaxf(red[j], red[j + off]);
        __syncthreads();
    }
    float m = red[0];
    __syncthreads();
    red[j] = expf(s2 - m);
    __syncthreads();
    for (int off = 64; off > 0; off >>= 1) {
        if (j < off) red[j] += red[j + off];
        __syncthreads();
    }
    float lse = m + logf(red[0]);
    out[g * 128 + j] = s2 - lse;
}

// ---------------------------------------------------------------------------

extern "C" void kernel_launch(void* const* d_in, const int* in_sizes, int n_in,
                              void* d_out, int out_size, void* d_ws, size_t ws_size,
                              hipStream_t stream) {
    (void)in_sizes; (void)n_in; (void)out_size; (void)ws_size;
    const float* x    = (const float*)d_in[0];
    const int*   ei   = (const int*)d_in[1];
    const int*   n2s  = (const int*)d_in[2];
    const int*   s2g  = (const int*)d_in[3];
    const float* W1a  = (const float*)d_in[4];
    const float* b1a  = (const float*)d_in[5];
    const float* W1b  = (const float*)d_in[6];
    const float* b1b  = (const float*)d_in[7];
    const float* cWa  = (const float*)d_in[8];
    const float* cba  = (const float*)d_in[9];
    const float* cWb  = (const float*)d_in[10];
    const float* cbb  = (const float*)d_in[11];
    const float* l1W  = (const float*)d_in[12];
    const float* l1b  = (const float*)d_in[13];
    const float* l2W  = (const float*)d_in[14];
    const float* l2b  = (const float*)d_in[15];
    float* out = (float*)d_out;

    // workspace layout (~35 MB)
    uint*  hb     = (uint*)d_ws;                        // N*64 (bf16 h, packed)
    uint*  habuf  = hb + (size_t)N_NODES * 64;          // N*64 (aggr / gemmA buf)
    int*   rowptr = (int*)(habuf + (size_t)N_NODES * 64); // N+2
    int*   cnt    = rowptr + (N_NODES + 2);             // N
    int*   bsum   = cnt + N_NODES;                      // 256
    int*   boff   = bsum + 256;                         // 256
    int*   csrc   = boff + 256;                         // E
    int*   rank   = csrc + N_EDGES;                     // E
    float* poolS  = (float*)(rank + N_EDGES);           // S*128
    float* poolG  = poolS + (size_t)SSUB * HDIM;        // G*128
    ushort* wt    = (ushort*)(poolG + (size_t)GGRAPH * HDIM); // 7*16384 bf16

    const int* srcA = ei;
    const int* dstA = ei + N_EDGES;
    const int nScanBlocks = (N_NODES + 255) / 256;      // 196
    const int nGemmBlocks = (N_NODES + 127) / 128;      // 391

    // --- CSR build (rank-based, atomic-free partitioned fill) ---
    hipMemsetAsync(cnt, 0, N_NODES * sizeof(int), stream);
    hipMemsetAsync(poolS, 0, (size_t)(SSUB + GGRAPH) * HDIM * sizeof(float), stream);
    k_hist2<<<N_EDGES / 256, 256, 0, stream>>>(dstA, cnt, rank);
    k_scan_reduce<<<nScanBlocks, 256, 0, stream>>>(cnt, bsum);
    k_scan_top<<<1, 256, 0, stream>>>(bsum, boff, nScanBlocks);
    k_scan_final<<<nScanBlocks, 256, 0, stream>>>(cnt, boff, rowptr);
    k_fill2<<<8 * FILL_Q, 256, 0, stream>>>(srcA, dstA, rank, rowptr, csrc);

    // --- weights -> bf16 transposed ---
    k_wconv<<<(7 * 16384) / 256, 256, 0, stream>>>(W1b, cWa, cWb, wt);

    // --- conv 1: fused aggr(x)+lin1a -> bf16, then MFMA gemm(W1b) -> hb ---
    k_conv1<<<nScanBlocks, 256, 0, stream>>>((const float2*)x, rowptr, csrc, W1a, b1a, habuf);
    k_gemm_mfma<0><<<nGemmBlocks, 256, 0, stream>>>((const ushort*)habuf, wt, b1b,
                                                    (ushort*)hb, nullptr, nullptr, N_NODES);

    // --- convs 2..4: aggr(hb)->habuf, gemmA in-place, gemmB -> hb
    //     (last gemmB fuses node->subgraph pooling, fp32 atomics) ---
    for (int i = 0; i < 3; ++i) {
        k_aggr128_bf16<<<N_NODES / 4, 256, 0, stream>>>(hb, rowptr, csrc, habuf);
        k_gemm_mfma<0><<<nGemmBlocks, 256, 0, stream>>>((const ushort*)habuf,
                                                        wt + (size_t)(1 + i) * 16384,
                                                        cba + i * HDIM,
                                                        (ushort*)habuf, nullptr, nullptr,
                                                        N_NODES);
        if (i < 2)
            k_gemm_mfma<0><<<nGemmBlocks, 256, 0, stream>>>((const ushort*)habuf,
                                                            wt + (size_t)(4 + i) * 16384,
                                                            cbb + i * HDIM,
                                                            (ushort*)hb, nullptr, nullptr,
                                                            N_NODES);
        else
            k_gemm_mfma<1><<<nGemmBlocks, 256, 0, stream>>>((const ushort*)habuf,
                                                            wt + (size_t)(4 + i) * 16384,
                                                            cbb + i * HDIM,
                                                            nullptr, n2s, poolS,
                                                            N_NODES);
    }

    // --- pooling level 2 + head ---
    k_pool2<<<(SSUB * HDIM) / 256, 256, 0, stream>>>(poolS, s2g, poolG);
    k_final<<<GGRAPH, 128, 0, stream>>>(poolG, l1W, l1b, l2W, l2b, out);
}